// Round 8
// baseline (323.682 us; speedup 1.0000x reference)
//
#include <hip/hip_runtime.h>
#include <math.h>
#include <stdint.h>
#include <stddef.h>

typedef __bf16 bf16;
typedef __bf16 bf16x8 __attribute__((ext_vector_type(8)));
typedef __bf16 bf16x4 __attribute__((ext_vector_type(4)));
typedef __bf16 bf16x2 __attribute__((ext_vector_type(2)));
typedef float  f32x4  __attribute__((ext_vector_type(4)));
typedef float  f32x4v __attribute__((ext_vector_type(4)));

typedef __attribute__((address_space(1))) const void* as1cv;
typedef __attribute__((address_space(3))) void*       as3v;

__device__ __forceinline__ f32x4 mfma16(bf16x8 a, bf16x8 b, f32x4 c) {
  return __builtin_amdgcn_mfma_f32_16x16x32_bf16(a, b, c, 0, 0, 0);
}

__device__ __forceinline__ void gload_lds16(const bf16* g, bf16* l) {
  __builtin_amdgcn_global_load_lds((as1cv)g, (as3v)l, 16, 0, 0);
}

// ---------------------------------------------------------------- fused convert
struct CvtTable {
  const float* s[9];
  bf16* d[9];
  int cum[10];
};

__global__ void cvt_all(CvtTable T, int total4) {
  int i = blockIdx.x * blockDim.x + threadIdx.x;
  int stride = gridDim.x * blockDim.x;
  for (; i < total4; i += stride) {
    int k = 0;
#pragma unroll
    for (int j = 1; j < 9; ++j) k += (i >= T.cum[j]) ? 1 : 0;
    int off = i - T.cum[k];
    f32x4v v = ((const f32x4v*)T.s[k])[off];
    bf16x4 o;
    o[0] = (bf16)v[0]; o[1] = (bf16)v[1]; o[2] = (bf16)v[2]; o[3] = (bf16)v[3];
    ((bf16x4*)T.d[k])[off] = o;
  }
}

// ---------------------------------------------------------------- GEMM core  C = A @ B^T
// 128x128 tile, BK=64, 512 thr / 8 waves (2x4, 64x32 out each), double-buffered
// XOR-swizzled LDS, 2-phase pipeline (R5 measured-best form).
__device__ __forceinline__ void gemm_core(
    const bf16* __restrict__ A, int lda,
    const bf16* __restrict__ B, int ldb, int Klen,
    float* __restrict__ Cf, bf16* __restrict__ Cb, int ldc,
    const float* __restrict__ bias, int bias_n, int m0, int n0)
{
  __shared__ __align__(16) bf16 Al[2][128 * 64];
  __shared__ __align__(16) bf16 Bl[2][128 * 64];
  const int tid = threadIdx.x;           // 0..511
  const int l = tid & 63;
  const int wid = tid >> 6;              // 0..7
  const int wr = wid >> 2, wc = wid & 3; // 2 x 4 wave grid
  const int lr = l & 15, lg = l >> 4;

  const int ch0 = tid, ch1 = tid + 512;
  const int ar0 = ch0 >> 3, ap0 = (ch0 & 7) ^ (ar0 & 7);
  const int ar1 = ch1 >> 3, ap1 = (ch1 & 7) ^ (ar1 & 7);
  const bf16* pA0 = A + (size_t)(m0 + ar0) * lda + ap0 * 8;
  const bf16* pA1 = A + (size_t)(m0 + ar1) * lda + ap1 * 8;
  const bf16* pB0 = B + (size_t)(n0 + ar0) * ldb + ap0 * 8;
  const bf16* pB1 = B + (size_t)(n0 + ar1) * ldb + ap1 * 8;
  bf16* dA0[2] = { &Al[0][ch0 * 8], &Al[1][ch0 * 8] };
  bf16* dA1[2] = { &Al[0][ch1 * 8], &Al[1][ch1 * 8] };
  bf16* dB0[2] = { &Bl[0][ch0 * 8], &Bl[1][ch0 * 8] };
  bf16* dB1[2] = { &Bl[0][ch1 * 8], &Bl[1][ch1 * 8] };

  auto STAGE = [&](int b) {
    gload_lds16(pA0, b ? dA0[1] : dA0[0]);
    gload_lds16(pA1, b ? dA1[1] : dA1[0]);
    gload_lds16(pB0, b ? dB0[1] : dB0[0]);
    gload_lds16(pB1, b ? dB1[1] : dB1[0]);
    pA0 += 64; pA1 += 64; pB0 += 64; pB1 += 64;
  };

  f32x4 z = {0.f, 0.f, 0.f, 0.f};
  f32x4 acc[4][2];
#pragma unroll
  for (int i = 0; i < 4; ++i)
#pragma unroll
    for (int j = 0; j < 2; ++j) acc[i][j] = z;

  STAGE(0);
  __syncthreads();
  int cur = 0;
  for (int k0 = 0; k0 < Klen; k0 += 64) {
    if (k0 + 64 < Klen) STAGE(cur ^ 1);
#pragma unroll
    for (int kk = 0; kk < 2; ++kk) {
      bf16x8 af[4], bfr[2];
#pragma unroll
      for (int i = 0; i < 4; ++i) {
        int row = wr * 64 + i * 16 + lr;
        int cq = kk * 4 + lg;
        af[i] = *(const bf16x8*)(&Al[cur][row * 64 + ((cq ^ (row & 7)) * 8)]);
      }
#pragma unroll
      for (int j = 0; j < 2; ++j) {
        int row = wc * 32 + j * 16 + lr;
        int cq = kk * 4 + lg;
        bfr[j] = *(const bf16x8*)(&Bl[cur][row * 64 + ((cq ^ (row & 7)) * 8)]);
      }
#pragma unroll
      for (int i = 0; i < 4; ++i)
#pragma unroll
        for (int j = 0; j < 2; ++j)
          acc[i][j] = mfma16(af[i], bfr[j], acc[i][j]);
    }
    __syncthreads();
    cur ^= 1;
  }

#pragma unroll
  for (int i = 0; i < 4; ++i)
#pragma unroll
    for (int j = 0; j < 2; ++j)
#pragma unroll
      for (int r = 0; r < 4; ++r) {
        int row = m0 + wr * 64 + i * 16 + lg * 4 + r;
        int col = n0 + wc * 32 + j * 16 + lr;
        float v = acc[i][j][r];
        if (bias != nullptr && col < bias_n) v += bias[col];
        if (Cf != nullptr) Cf[(size_t)row * ldc + col] = v;
        else               Cb[(size_t)row * ldc + col] = (bf16)v;
      }
}

// Split-K x2: blockIdx.z selects K-half and partial buffer.
template<bool OUTF32>
__global__ __launch_bounds__(512) void gemm_splitk(
    const bf16* __restrict__ A, int lda,
    const bf16* __restrict__ B, int ldb, int Khalf,
    float* __restrict__ F0, float* __restrict__ F1,
    bf16* __restrict__ H0, bf16* __restrict__ H1, int ldc)
{
  int zz = blockIdx.z;
  gemm_core(A + zz * Khalf, lda, B + zz * Khalf, ldb, Khalf,
            OUTF32 ? (zz ? F1 : F0) : nullptr,
            OUTF32 ? nullptr : (zz ? H1 : H0), ldc,
            nullptr, 0, blockIdx.y * 128, blockIdx.x * 128);
}

// Two independent GEMMs in one launch (full K).
__global__ __launch_bounds__(512) void gemm_bt_dual(
    const bf16* __restrict__ A0, int lda0, const bf16* __restrict__ B0, int K0,
    bf16* __restrict__ C0, int ldc0, int nbx0,
    const bf16* __restrict__ A1, int lda1, const bf16* __restrict__ B1, int K1,
    bf16* __restrict__ C1, int ldc1, int nbx1)
{
  int bid = blockIdx.x;
  if (bid < nbx0 * 16) {
    gemm_core(A0, lda0, B0, K0, K0, nullptr, C0, ldc0, nullptr, 0,
              (bid / nbx0) * 128, (bid % nbx0) * 128);
  } else {
    bid -= nbx0 * 16;
    gemm_core(A1, lda1, B1, K1, K1, nullptr, C1, ldc1, nullptr, 0,
              (bid / nbx1) * 128, (bid % nbx1) * 128);
  }
}

// ---------------------------------------------------------------- reduces
__global__ void reduce_c(const bf16* __restrict__ P0, const bf16* __restrict__ P1,
                         const float* __restrict__ bias, bf16* __restrict__ c_all)
{
  const int n8 = 2048 * 2176 / 8;
  int i = blockIdx.x * blockDim.x + threadIdx.x;
  int stride = gridDim.x * blockDim.x;
  for (; i < n8; i += stride) {
    int col8 = (i % 272) * 8;
    bf16x8 a = ((const bf16x8*)P0)[i];
    bf16x8 b = ((const bf16x8*)P1)[i];
    bf16x8 o;
    if (col8 < 1536) {
#pragma unroll
      for (int j = 0; j < 8; ++j)
        o[j] = (bf16)((float)a[j] + (float)b[j] + bias[col8 + j]);
    } else {
#pragma unroll
      for (int j = 0; j < 8; ++j)
        o[j] = (bf16)((float)a[j] + (float)b[j]);
    }
    ((bf16x8*)c_all)[i] = o;
  }
}

__global__ void reduce_f(const float* __restrict__ P0, const float* __restrict__ P1,
                         float* __restrict__ out)
{
  const int n4 = 2048 * 2048 / 4;
  int i = blockIdx.x * blockDim.x + threadIdx.x;
  int stride = gridDim.x * blockDim.x;
  for (; i < n4; i += stride) {
    f32x4v a = ((const f32x4v*)P0)[i];
    f32x4v b = ((const f32x4v*)P1)[i];
    f32x4v o = a + b;
    ((f32x4v*)out)[i] = o;
  }
}

// ---------------------------------------------------------------- RoPE + V-transpose (fused)
__global__ void rope_tv(const bf16* __restrict__ QA, const bf16* __restrict__ c_all,
                        const float* __restrict__ cosb, const float* __restrict__ sinb,
                        bf16* __restrict__ Qr, bf16* __restrict__ Kr,
                        const bf16* __restrict__ KV, bf16* __restrict__ Vt)
{
  int bid = blockIdx.x;
  if (bid < 2048) {
    int t = bid;
    for (int idx = threadIdx.x; idx < 544; idx += 256) {
      if (idx < 512) {
        int h = idx >> 5, p = idx & 31;
        float x1 = (float)QA[(size_t)t * 3072 + 2048 + h * 64 + p];
        float x2 = (float)QA[(size_t)t * 3072 + 2048 + h * 64 + 32 + p];
        float c = cosb[t * 32 + p], s = sinb[t * 32 + p];
        Qr[(size_t)t * 1024 + h * 64 + p]      = (bf16)( x1 * c + x2 * s);
        Qr[(size_t)t * 1024 + h * 64 + 32 + p] = (bf16)(-x1 * s + x2 * c);
      } else {
        int p = idx - 512;
        float x1 = (float)c_all[(size_t)t * 2176 + 2048 + p];
        float x2 = (float)c_all[(size_t)t * 2176 + 2048 + 32 + p];
        float c = cosb[t * 32 + p], s = sinb[t * 32 + p];
        Kr[(size_t)t * 64 + p]      = (bf16)( x1 * c + x2 * s);
        Kr[(size_t)t * 64 + 32 + p] = (bf16)(-x1 * s + x2 * c);
      }
    }
  } else {
    __shared__ bf16 tile[32][33];
    int tb = bid - 2048;
    int t0 = (tb & 63) * 32, c0 = (tb >> 6) * 32;
    int tx = threadIdx.x & 31, ty = threadIdx.x >> 5;
#pragma unroll
    for (int r = 0; r < 4; ++r)
      tile[ty + r * 8][tx] = KV[(size_t)(t0 + ty + r * 8) * 4096 + 2048 + c0 + tx];
    __syncthreads();
#pragma unroll
    for (int r = 0; r < 4; ++r)
      Vt[(size_t)(c0 + ty + r * 8) * 2048 + t0 + tx] = tile[tx][ty + r * 8];
  }
}

// ---------------------------------------------------------------- flash attention
// 1024 blocks x 2 waves (32 q-rows/block) -> 4 independent blocks/CU.
// LDS exactly 40KB: merged K|Kr tile [2][32][192] + V tile [2][128][32].
// Swapped-operand compute, lane-local stats, in-register P distribution
// via 8 shfl (no P LDS round-trip), defer-max, counted-vmcnt staging.
__global__ __launch_bounds__(128) void attn_kernel(
    const bf16* __restrict__ QA,  // 2048 x 3072
    const bf16* __restrict__ Qr,  // 2048 x 1024
    const bf16* __restrict__ KV,  // 2048 x 4096 ([Kfull|Vfull])
    const bf16* __restrict__ Kr,  // 2048 x 64
    const bf16* __restrict__ Vt,  // 2048(c) x 2048(t)
    bf16* __restrict__ heads)     // 2048 x 2048
{
  __shared__ __align__(16) bf16 L[2][10240];  // [0..6143]=K(32x192)  [6144..10239]=V(128x32)

  const int tid = threadIdx.x;   // 0..127
  const int l = tid & 63;
  const int wid = tid >> 6;      // 0..1
  const int lr = l & 15, lg = l >> 4;

  // 2 heads/XCD; per-CU rounds give qt sums = const (load balance).
  const int wg = blockIdx.x;
  const int xcd = wg & 7, inx = wg >> 3;   // inx 0..127
  const int rnd = inx >> 5, c = inx & 31;
  const int h = xcd * 2 + (rnd >> 1);
  const int qt = (rnd == 0) ? (63 - c) : (rnd == 1) ? (31 - c) : (rnd == 2) ? c : (32 + c);
  const int q0 = qt * 32 + wid * 16;
  const int q = q0 + lr;

  const float scale = 0.041666666666666664f;  // 1/sqrt(576)
  f32x4 z = {0.f, 0.f, 0.f, 0.f};

  // ---- staging init (pre-swizzled sources, rule #21) ----
  // K-part: 768 granules (32 rows x 24), 6 per thread
  const bf16* gK[6]; int sK[6]; int chK[6];
#pragma unroll
  for (int i = 0; i < 6; ++i) {
    int ch = i * 128 + tid;
    int row = ch / 24, gcol = ch - row * 24;
    int lgc = (gcol & 24) | ((gcol & 7) ^ (row & 7));
    if (lgc < 16) { gK[i] = KV + (size_t)row * 4096 + h * 128 + lgc * 8; sK[i] = 32 * 4096; }
    else          { gK[i] = Kr + (size_t)row * 64 + (lgc - 16) * 8;      sK[i] = 32 * 64; }
    chK[i] = ch;
  }
  // V-part: 512 granules (128 rows x 4), 4 per thread
  const bf16* gV[4]; int chV[4];
#pragma unroll
  for (int j = 0; j < 4; ++j) {
    int ch = j * 128 + tid;
    int r = ch >> 2, p = ch & 3;
    int cb = p ^ ((r >> 1) & 3);
    gV[j] = Vt + (size_t)(h * 128 + r) * 2048 + cb * 8;
    chV[j] = ch;
  }

  auto STAGE = [&](int b) {
#pragma unroll
    for (int i = 0; i < 6; ++i) {
      gload_lds16(gK[i], &L[b][chK[i] * 8]);
      gK[i] += sK[i];
    }
#pragma unroll
    for (int j = 0; j < 4; ++j) {
      gload_lds16(gV[j], &L[b][6144 + chV[j] * 8]);
      gV[j] += 32;
    }
  };

  // Q B-fragments (col = q), d = 192 over 6 slices of 32
  bf16x8 aq[6];
#pragma unroll
  for (int kc = 0; kc < 4; ++kc)
    aq[kc] = *(const bf16x8*)&QA[(size_t)q * 3072 + h * 128 + kc * 32 + lg * 8];
#pragma unroll
  for (int kc = 4; kc < 6; ++kc)
    aq[kc] = *(const bf16x8*)&Qr[(size_t)q * 1024 + h * 64 + (kc - 4) * 32 + lg * 8];

  // shfl source lanes for P distribution (loop-invariant)
  const int sl0 = lr + 16 * ((lg & 1) * 2);
  const int sl1 = sl0 + 16;
  const bool hiT = (lg >> 1) != 0;

  float m_run = -1e30f, l_run = 0.f;
  f32x4 acc[8];
#pragma unroll
  for (int cc = 0; cc < 8; ++cc) acc[cc] = z;

  const int nIter = qt + 1;
  STAGE(0);
  int cur = 0;
  for (int st = 0; st < nIter; ++st) {
    const int s0 = st * 32;
    if (st + 1 < nIter) {
      STAGE(cur ^ 1);
      asm volatile("s_waitcnt vmcnt(10)" ::: "memory");
    } else {
      asm volatile("s_waitcnt vmcnt(0)" ::: "memory");
    }
    __builtin_amdgcn_s_barrier();
    __builtin_amdgcn_sched_barrier(0);

    // QK^T (swapped): A = K rows from LDS, B = Q registers. 2 chains per t.
    f32x4 scA[2], scB[2];
    scA[0] = z; scA[1] = z; scB[0] = z; scB[1] = z;
#pragma unroll
    for (int t = 0; t < 2; ++t) {
      const int rr = t * 16 + lr;
#pragma unroll
      for (int kc = 0; kc < 6; ++kc) {
        int g = kc * 4 + lg;
        int gc = (g & 24) | ((g & 7) ^ (rr & 7));
        bf16x8 ka = *(const bf16x8*)&L[cur][rr * 192 + gc * 8];
        if (kc < 3) scA[t] = mfma16(ka, aq[kc], scA[t]);
        else        scB[t] = mfma16(ka, aq[kc], scB[t]);
      }
    }
    // V fragments prefetch (independent of softmax)
    bf16x8 va[8];
#pragma unroll
    for (int cc = 0; cc < 8; ++cc) {
      int rv = cc * 16 + lr;
      va[cc] = *(const bf16x8*)&L[cur][6144 + rv * 32 + ((lg ^ ((rv >> 1) & 3)) * 8)];
    }
    f32x4 sc[2];
    sc[0] = scA[0] + scB[0];
    sc[1] = scA[1] + scB[1];

    // softmax (lane-local stats), causal mask near diagonal only
    float pv[2][4];
    float mx = -1e30f;
    if (s0 + 31 > q0) {
#pragma unroll
      for (int t = 0; t < 2; ++t)
#pragma unroll
        for (int r = 0; r < 4; ++r) {
          int k = s0 + t * 16 + lg * 4 + r;
          float v = sc[t][r] * scale;
          if (k > q) v = -1e30f;
          pv[t][r] = v;
          mx = fmaxf(mx, v);
        }
    } else {
#pragma unroll
      for (int t = 0; t < 2; ++t)
#pragma unroll
        for (int r = 0; r < 4; ++r) {
          float v = sc[t][r] * scale;
          pv[t][r] = v;
          mx = fmaxf(mx, v);
        }
    }
    mx = fmaxf(mx, __shfl_xor(mx, 16, 64));
    mx = fmaxf(mx, __shfl_xor(mx, 32, 64));
    if (!__all(mx - m_run <= 8.f)) {          // defer-max (T13)
      float mnew = fmaxf(m_run, mx);
      float alpha = __expf(m_run - mnew);
      l_run *= alpha;
#pragma unroll
      for (int cc = 0; cc < 8; ++cc)
#pragma unroll
        for (int r = 0; r < 4; ++r) acc[cc][r] *= alpha;
      m_run = mnew;
    }
    float sum = 0.f;
#pragma unroll
    for (int t = 0; t < 2; ++t)
#pragma unroll
      for (int r = 0; r < 4; ++r) {
        float e = __expf(pv[t][r] - m_run);
        pv[t][r] = e;
        sum += e;
      }
    sum += __shfl_xor(sum, 16, 64);
    sum += __shfl_xor(sum, 32, 64);
    l_run += sum;

    // P^T distribution in-register: pack 4 words, 8 shfl, select by t.
    union { bf16x2 h2; int u; } wv[2][2];
#pragma unroll
    for (int t = 0; t < 2; ++t)
#pragma unroll
      for (int hf = 0; hf < 2; ++hf) {
        wv[t][hf].h2[0] = (bf16)pv[t][2 * hf];
        wv[t][hf].h2[1] = (bf16)pv[t][2 * hf + 1];
      }
    union { int u[4]; bf16x8 v; } pa;
    {
      int a0, a1;
      a0 = __shfl(wv[0][0].u, sl0, 64); a1 = __shfl(wv[1][0].u, sl0, 64);
      pa.u[0] = hiT ? a1 : a0;
      a0 = __shfl(wv[0][1].u, sl0, 64); a1 = __shfl(wv[1][1].u, sl0, 64);
      pa.u[1] = hiT ? a1 : a0;
      a0 = __shfl(wv[0][0].u, sl1, 64); a1 = __shfl(wv[1][0].u, sl1, 64);
      pa.u[2] = hiT ? a1 : a0;
      a0 = __shfl(wv[0][1].u, sl1, 64); a1 = __shfl(wv[1][1].u, sl1, 64);
      pa.u[3] = hiT ? a1 : a0;
    }

    // PV (O^T): A = V fragments, B = P^T
#pragma unroll
    for (int cc = 0; cc < 8; ++cc)
      acc[cc] = mfma16(va[cc], pa.v, acc[cc]);

    __builtin_amdgcn_sched_barrier(0);
    __builtin_amdgcn_s_barrier();   // all waves done reading cur before re-stage
    cur ^= 1;
  }

  const float inv = 1.f / l_run;
#pragma unroll
  for (int cc = 0; cc < 8; ++cc) {
    bf16x4 o;
#pragma unroll
    for (int r = 0; r < 4; ++r) o[r] = (bf16)(acc[cc][r] * inv);
    *(bf16x4*)&heads[(size_t)q * 2048 + h * 128 + cc * 16 + lg * 4] = o;
  }
}

// ---------------------------------------------------------------- launch
extern "C" void kernel_launch(void* const* d_in, const int* in_sizes, int n_in,
                              void* d_out, int out_size, void* d_ws, size_t ws_size,
                              hipStream_t stream) {
  (void)in_sizes; (void)n_in; (void)out_size; (void)ws_size;
  const float* x      = (const float*)d_in[0];
  const float* cosp   = (const float*)d_in[1];
  const float* sinp   = (const float*)d_in[2];
  const float* Wq_d   = (const float*)d_in[3];
  const float* Wq_d_b = (const float*)d_in[4];
  const float* Wkv_d  = (const float*)d_in[5];
  const float* Wq_u   = (const float*)d_in[6];
  const float* Wk_u   = (const float*)d_in[7];
  const float* Wv_u   = (const float*)d_in[8];
  const float* W_qr   = (const float*)d_in[9];
  const float* W_kr   = (const float*)d_in[10];
  const float* W_out  = (const float*)d_in[11];

  char* ws = (char*)d_ws;
  size_t off = 0;
  auto alloc = [&](size_t bytes) {
    char* p = ws + off;
    off += (bytes + 255) & ~(size_t)255;
    return p;
  };
  bf16* xb    = (bf16*)alloc((size_t)2048 * 2048 * 2);  // Vt after G1; G4-P0 region
  bf16* Wcat  = (bf16*)alloc((size_t)2176 * 2048 * 2);  // (xb+Wcat = 17.3MB contiguous)
  bf16* c_all = (bf16*)alloc((size_t)2048 * 2176 * 2);
  bf16* Wqu   = (bf16*)alloc((size_t)3072 * 1536 * 2);  // reused as heads
  bf16* QA    = (bf16*)alloc((size_t)2048 * 3072 * 2);  // G1-P0 before G2; G4-P1 region
  bf16* Wkvu  = (bf16*)alloc((size_t)4096 * 512 * 2);   // (QA+Wkvu = 16.78MB exact)
  bf16* KV    = (bf16*)alloc((size_t)2048 * 4096 * 2);  // G1-P1 before G3
  bf16* Qr    = (bf16*)alloc((size_t)2048 * 1024 * 2);
  bf16* Kr    = (bf16*)alloc((size_t)2048 * 64 * 2);
  bf16* Wout  = (bf16*)alloc((size_t)2048 * 2048 * 2);
  bf16* Vt    = xb;
  bf16* heads = Wqu;
  bf16* P0b   = QA;            // G1 bf16 partial 0 (8.9MB < 12.6MB)
  bf16* P1b   = KV;            // G1 bf16 partial 1 (8.9MB < 16.8MB)
  float* P0f  = (float*)xb;    // G4 f32 partial 0 (16.78MB <= xb+Wcat)
  float* P1f  = (float*)QA;    // G4 f32 partial 1 (16.78MB == QA+Wkvu)

  CvtTable T;
  const float* srcs[9] = { x, Wq_d, Wkv_d, W_kr, Wq_u, W_qr, Wk_u, Wv_u, W_out };
  bf16* dsts[9] = { xb, Wcat, Wcat + (size_t)1536 * 2048, Wcat + (size_t)2048 * 2048,
                    Wqu, Wqu + (size_t)2048 * 1536, Wkvu, Wkvu + (size_t)2048 * 512, Wout };
  size_t ns[9] = { (size_t)2048 * 2048, (size_t)1536 * 2048, (size_t)512 * 2048,
                   (size_t)64 * 2048, (size_t)2048 * 1536, (size_t)1024 * 1536,
                   (size_t)2048 * 512, (size_t)2048 * 512, (size_t)2048 * 2048 };
  int cum = 0;
  for (int i = 0; i < 9; ++i) {
    T.s[i] = srcs[i]; T.d[i] = dsts[i]; T.cum[i] = cum;
    cum += (int)(ns[i] / 4);
  }
  T.cum[9] = cum;
  cvt_all<<<2048, 256, 0, stream>>>(T, cum);

  // G1 split-K: partials (bf16) then reduce(+bias) -> c_all
  gemm_splitk<false><<<dim3(17, 16, 2), 512, 0, stream>>>(
      xb, 2048, Wcat, 2048, 1024, nullptr, nullptr, P0b, P1b, 2176);
  reduce_c<<<2176, 256, 0, stream>>>(P0b, P1b, Wq_d_b, c_all);
  // G2 + G3 fused launch: QA = cq @ [Wq_u;W_qr]^T ; KV = ckv @ [Wk_u;Wv_u]^T
  gemm_bt_dual<<<24 * 16 + 32 * 16, 512, 0, stream>>>(
      c_all, 2176, Wqu, 1536, QA, 3072, 24,
      c_all + 1536, 2176, Wkvu, 512, KV, 4096, 32);
  // RoPE + V transpose fused
  rope_tv<<<2048 + 4096, 256, 0, stream>>>(QA, c_all, cosp, sinp, Qr, Kr, KV, Vt);
  attn_kernel<<<1024, 128, 0, stream>>>(QA, Qr, KV, Kr, Vt, heads);
  // G4 split-K: f32 partials then reduce -> d_out
  gemm_splitk<true><<<dim3(16, 16, 2), 512, 0, stream>>>(
      heads, 2048, Wout, 2048, 1024, P0f, P1f, nullptr, nullptr, 2048);
  reduce_f<<<2048, 256, 0, stream>>>(P0f, P1f, (float*)d_out);
}